// Round 1
// baseline (422.972 us; speedup 1.0000x reference)
//
#include <hip/hip_runtime.h>

#define M_DIM 16384
#define N_DIM 2048
#define K_DIM 2048
#define KB    (K_DIM / 128)
#define BM 128
#define BN 128
#define BK 64

typedef __bf16 bf16x8 __attribute__((ext_vector_type(8)));
typedef float  f32x4  __attribute__((ext_vector_type(4)));

__device__ __forceinline__ unsigned short f32_to_bf16_rne(float f) {
    unsigned int u = __float_as_uint(f);
    u += 0x7FFFu + ((u >> 16) & 1u);
    return (unsigned short)(u >> 16);
}

// ---- Pass 1: activation quant (amax/448, f32 div, HW fp8 RNE) + dequant to bf16 ----
// One wave handles one 128-element K-block; blocks are contiguous in row-major x.
__global__ __launch_bounds__(256) void quant_x_kernel(const float* __restrict__ x,
                                                      unsigned short* __restrict__ xdq) {
    const int gw   = blockIdx.x * 4 + (threadIdx.x >> 6);
    const int lane = threadIdx.x & 63;
    const size_t base = (size_t)gw * 128;
    const float2 v = *(const float2*)(x + base + lane * 2);
    float amax = fmaxf(fabsf(v.x), fabsf(v.y));
#pragma unroll
    for (int m = 32; m >= 1; m >>= 1)
        amax = fmaxf(amax, __shfl_xor(amax, m, 64));
    float s = amax / 448.0f;          // true f32 division (matches reference rounding)
    if (s == 0.0f) s = 1.0f;
    const float q0 = v.x / s;
    const float q1 = v.y / s;
    const int p = __builtin_amdgcn_cvt_pk_fp8_f32(q0, q1, 0, false);  // OCP e4m3fn RNE on gfx950
    const float d0 = __builtin_amdgcn_cvt_f32_fp8(p, 0) * s;
    const float d1 = __builtin_amdgcn_cvt_f32_fp8(p, 1) * s;
    const unsigned int out = (unsigned int)f32_to_bf16_rne(d0) |
                             ((unsigned int)f32_to_bf16_rne(d1) << 16);
    ((unsigned int*)xdq)[base / 2 + lane] = out;
}

// ---- Pass 2: weight dequant (w_fp8 * per-128x128-block scale) to bf16 ----
__global__ __launch_bounds__(256) void dequant_w_kernel(const float* __restrict__ w,
                                                        const float* __restrict__ wscale,
                                                        unsigned short* __restrict__ wdq) {
    const size_t e = ((size_t)blockIdx.x * 256 + threadIdx.x) * 2;
    const float2 v = *(const float2*)(w + e);
    const int n = (int)(e >> 11);     // K_DIM = 2048
    const int k = (int)(e & 2047);
    const float s = wscale[(n >> 7) * KB + (k >> 7)];
    const unsigned int out = (unsigned int)f32_to_bf16_rne(v.x * s) |
                             ((unsigned int)f32_to_bf16_rne(v.y * s) << 16);
    ((unsigned int*)wdq)[e / 2] = out;
}

// ---- Pass 3: C = A @ B^T, A [M,K] bf16 row-major, B [N,K] bf16 row-major, C [M,N] f32 ----
// m97-style: 128x128 tile, BK=64, 4 waves in 2x2, 4x4 16x16x32 frags/wave,
// global_load_lds width=16 staging, 2-barrier K-loop.
__global__ __launch_bounds__(256) void gemm_bt_kernel(const unsigned short* __restrict__ A,
                                                      const unsigned short* __restrict__ B,
                                                      float* __restrict__ C) {
    __shared__ __align__(16) unsigned short As[BM * BK];
    __shared__ __align__(16) unsigned short Bs[BN * BK];

    const int tid  = threadIdx.x;
    const int lane = tid & 63;
    const int wave = tid >> 6;
    const int wm   = (wave >> 1) * 64;
    const int wn   = (wave & 1) * 64;
    const int quad = lane >> 4;
    const int l16  = lane & 15;

    const int m0 = blockIdx.y * BM;
    const int n0 = blockIdx.x * BN;

    f32x4 acc[4][4] = {};

    // staging: chunk c = i*256 + tid; LDS bytes c*16; global row = c>>3, kchunk = c&7
    const int srow = tid >> 3;   // 0..31
    const int skc  = tid & 7;    // 0..7
    const unsigned short* gA = A + (size_t)(m0 + srow) * K_DIM + skc * 8;
    const unsigned short* gB = B + (size_t)(n0 + srow) * K_DIM + skc * 8;

    for (int kt = 0; kt < K_DIM / BK; ++kt) {
        const int k0 = kt * BK;
#pragma unroll
        for (int i = 0; i < 4; ++i) {
            __builtin_amdgcn_global_load_lds(
                (__attribute__((address_space(1))) void*)(gA + (size_t)(i * 32) * K_DIM + k0),
                (__attribute__((address_space(3))) void*)(As + (i * 256 + wave * 64) * 8),
                16, 0, 0);
        }
#pragma unroll
        for (int i = 0; i < 4; ++i) {
            __builtin_amdgcn_global_load_lds(
                (__attribute__((address_space(1))) void*)(gB + (size_t)(i * 32) * K_DIM + k0),
                (__attribute__((address_space(3))) void*)(Bs + (i * 256 + wave * 64) * 8),
                16, 0, 0);
        }
        __syncthreads();
#pragma unroll
        for (int ks = 0; ks < BK; ks += 32) {
            bf16x8 af[4], bfr[4];
#pragma unroll
            for (int i = 0; i < 4; ++i)
                af[i] = *(const bf16x8*)(As + (wm + i * 16 + l16) * BK + ks + quad * 8);
#pragma unroll
            for (int j = 0; j < 4; ++j)
                bfr[j] = *(const bf16x8*)(Bs + (wn + j * 16 + l16) * BK + ks + quad * 8);
#pragma unroll
            for (int i = 0; i < 4; ++i)
#pragma unroll
                for (int j = 0; j < 4; ++j)
                    acc[i][j] = __builtin_amdgcn_mfma_f32_16x16x32_bf16(af[i], bfr[j], acc[i][j], 0, 0, 0);
        }
        __syncthreads();
    }

    // epilogue: C/D layout row = quad*4 + reg, col = lane&15
#pragma unroll
    for (int i = 0; i < 4; ++i) {
        const int row = m0 + wm + i * 16 + quad * 4;
#pragma unroll
        for (int j = 0; j < 4; ++j) {
            const int col = n0 + wn + j * 16 + l16;
            float* cp = C + (size_t)row * N_DIM + col;
#pragma unroll
            for (int r = 0; r < 4; ++r)
                cp[(size_t)r * N_DIM] = acc[i][j][r];
        }
    }
}

extern "C" void kernel_launch(void* const* d_in, const int* in_sizes, int n_in,
                              void* d_out, int out_size, void* d_ws, size_t ws_size,
                              hipStream_t stream) {
    const float* x      = (const float*)d_in[0];
    const float* wfp8   = (const float*)d_in[1];
    const float* wscale = (const float*)d_in[2];
    float* out = (float*)d_out;

    unsigned short* xdq = (unsigned short*)d_ws;                    // M*K bf16 = 67.1 MB
    unsigned short* wdq = xdq + (size_t)M_DIM * K_DIM;              // N*K bf16 = 8.4 MB

    quant_x_kernel<<<(M_DIM * KB) / 4, 256, 0, stream>>>(x, xdq);
    dequant_w_kernel<<<(N_DIM * K_DIM / 2) / 256, 256, 0, stream>>>(wfp8, wscale, wdq);
    gemm_bt_kernel<<<dim3(N_DIM / BN, M_DIM / BM), 256, 0, stream>>>(xdq, wdq, out);
}

// Round 2
// 372.978 us; speedup vs baseline: 1.1340x; 1.1340x over previous
//
#include <hip/hip_runtime.h>

#define M_DIM 16384
#define N_DIM 2048
#define K_DIM 2048
#define KB    (K_DIM / 128)
#define BM 128
#define BN 128
#define BK 64

// quant grid partition: 256 threads x 4 floats per block
#define XGRID (M_DIM * K_DIM / 1024)   // 32768
#define WGRID (N_DIM * K_DIM / 1024)   // 4096

typedef __bf16 bf16x8 __attribute__((ext_vector_type(8)));
typedef float  f32x4  __attribute__((ext_vector_type(4)));

__device__ __forceinline__ unsigned short f32_to_bf16_rne(float f) {
    unsigned int u = __float_as_uint(f);
    u += 0x7FFFu + ((u >> 16) & 1u);
    return (unsigned short)(u >> 16);
}

// ---- Fused pass: activation quant+dequant (blocks [0,XGRID)) and weight dequant ----
__global__ __launch_bounds__(256) void quant_all_kernel(const float* __restrict__ x,
                                                        unsigned short* __restrict__ xdq,
                                                        const float* __restrict__ w,
                                                        const float* __restrict__ wscale,
                                                        unsigned short* __restrict__ wdq) {
    const int tid = threadIdx.x;
    if (blockIdx.x < XGRID) {
        // 32 consecutive lanes (half-wave) cover one 128-elem K-block
        const size_t base = ((size_t)blockIdx.x * 256 + tid) * 4;
        const float4 v = *(const float4*)(x + base);
        float amax = fmaxf(fmaxf(fabsf(v.x), fabsf(v.y)), fmaxf(fabsf(v.z), fabsf(v.w)));
#pragma unroll
        for (int m = 16; m >= 1; m >>= 1)
            amax = fmaxf(amax, __shfl_xor(amax, m, 64));
        float s = amax / 448.0f;                  // true f32 div (matches reference)
        if (s == 0.0f) s = 1.0f;
        const int p01 = __builtin_amdgcn_cvt_pk_fp8_f32(v.x / s, v.y / s, 0, false);
        const int p23 = __builtin_amdgcn_cvt_pk_fp8_f32(v.z / s, v.w / s, 0, false);
        const float d0 = __builtin_amdgcn_cvt_f32_fp8(p01, 0) * s;
        const float d1 = __builtin_amdgcn_cvt_f32_fp8(p01, 1) * s;
        const float d2 = __builtin_amdgcn_cvt_f32_fp8(p23, 0) * s;
        const float d3 = __builtin_amdgcn_cvt_f32_fp8(p23, 1) * s;
        uint2 out;
        out.x = (unsigned int)f32_to_bf16_rne(d0) | ((unsigned int)f32_to_bf16_rne(d1) << 16);
        out.y = (unsigned int)f32_to_bf16_rne(d2) | ((unsigned int)f32_to_bf16_rne(d3) << 16);
        *(uint2*)(xdq + base) = out;
    } else {
        const size_t e = ((size_t)(blockIdx.x - XGRID) * 256 + tid) * 4;
        const float4 v = *(const float4*)(w + e);
        const int n = (int)(e >> 11);
        const int k = (int)(e & 2047);
        const float s = wscale[(n >> 7) * KB + (k >> 7)];   // k..k+3 same 128-block
        uint2 out;
        out.x = (unsigned int)f32_to_bf16_rne(v.x * s) | ((unsigned int)f32_to_bf16_rne(v.y * s) << 16);
        out.y = (unsigned int)f32_to_bf16_rne(v.z * s) | ((unsigned int)f32_to_bf16_rne(v.w * s) << 16);
        *(uint2*)(wdq + e) = out;
    }
}

// ---- GEMM: C = A @ B^T, bf16 in, f32 out. 128x128 tile, BK=64, XOR-swizzled LDS ----
// Physical LDS chunk (row, c) holds logical (row, c ^ (row&7)); staging permutes the
// global source (global_load_lds dest must stay lane-contiguous), fragment reads XOR.
__global__ __launch_bounds__(256) void gemm_bt_kernel(const unsigned short* __restrict__ A,
                                                      const unsigned short* __restrict__ B,
                                                      float* __restrict__ C) {
    __shared__ __align__(16) unsigned short As[BM * BK];
    __shared__ __align__(16) unsigned short Bs[BN * BK];

    const int tid  = threadIdx.x;
    const int lane = tid & 63;
    const int wave = tid >> 6;
    const int wm   = (wave >> 1) * 64;
    const int wn   = (wave & 1) * 64;
    const int quad = lane >> 4;
    const int l16  = lane & 15;

    // grid swapped: x carries M so XCD round-robin partitions A-slabs
    const int m0 = blockIdx.x * BM;
    const int n0 = blockIdx.y * BN;

    f32x4 acc[4][4] = {};

    const int srow = tid >> 3;                    // 0..31
    const int scol = (tid & 7) ^ (srow & 7);      // swizzled global source chunk
    const unsigned short* gA = A + (size_t)(m0 + srow) * K_DIM + scol * 8;
    const unsigned short* gB = B + (size_t)(n0 + srow) * K_DIM + scol * 8;

    for (int kt = 0; kt < K_DIM / BK; ++kt) {
        const int k0 = kt * BK;
#pragma unroll
        for (int i = 0; i < 4; ++i) {
            __builtin_amdgcn_global_load_lds(
                (__attribute__((address_space(1))) void*)(gA + (size_t)(i * 32) * K_DIM + k0),
                (__attribute__((address_space(3))) void*)(As + (i * 256 + wave * 64) * 8),
                16, 0, 0);
        }
#pragma unroll
        for (int i = 0; i < 4; ++i) {
            __builtin_amdgcn_global_load_lds(
                (__attribute__((address_space(1))) void*)(gB + (size_t)(i * 32) * K_DIM + k0),
                (__attribute__((address_space(3))) void*)(Bs + (i * 256 + wave * 64) * 8),
                16, 0, 0);
        }
        __syncthreads();
#pragma unroll
        for (int ks = 0; ks < BK; ks += 32) {
            const int c = (ks >> 3) + quad;       // logical 16B chunk index
            const int swz = (c ^ (l16 & 7)) * 8;  // physical offset in ushorts
            bf16x8 af[4], bfr[4];
#pragma unroll
            for (int i = 0; i < 4; ++i)
                af[i] = *(const bf16x8*)(As + (wm + i * 16 + l16) * BK + swz);
#pragma unroll
            for (int j = 0; j < 4; ++j)
                bfr[j] = *(const bf16x8*)(Bs + (wn + j * 16 + l16) * BK + swz);
#pragma unroll
            for (int i = 0; i < 4; ++i)
#pragma unroll
                for (int j = 0; j < 4; ++j)
                    acc[i][j] = __builtin_amdgcn_mfma_f32_16x16x32_bf16(af[i], bfr[j], acc[i][j], 0, 0, 0);
        }
        __syncthreads();
    }

    // C/D layout: row = quad*4 + reg, col = lane&15
#pragma unroll
    for (int i = 0; i < 4; ++i) {
        const int row = m0 + wm + i * 16 + quad * 4;
#pragma unroll
        for (int j = 0; j < 4; ++j) {
            const int col = n0 + wn + j * 16 + l16;
            float* cp = C + (size_t)row * N_DIM + col;
#pragma unroll
            for (int r = 0; r < 4; ++r)
                cp[(size_t)r * N_DIM] = acc[i][j][r];
        }
    }
}

extern "C" void kernel_launch(void* const* d_in, const int* in_sizes, int n_in,
                              void* d_out, int out_size, void* d_ws, size_t ws_size,
                              hipStream_t stream) {
    const float* x      = (const float*)d_in[0];
    const float* wfp8   = (const float*)d_in[1];
    const float* wscale = (const float*)d_in[2];
    float* out = (float*)d_out;

    unsigned short* xdq = (unsigned short*)d_ws;                    // M*K bf16
    unsigned short* wdq = xdq + (size_t)M_DIM * K_DIM;              // N*K bf16

    quant_all_kernel<<<XGRID + WGRID, 256, 0, stream>>>(x, xdq, wfp8, wscale, wdq);
    gemm_bt_kernel<<<dim3(M_DIM / BM, N_DIM / BN), 256, 0, stream>>>(xdq, wdq, out);
}